// Round 6
// baseline (389.804 us; speedup 1.0000x reference)
//
#include <hip/hip_runtime.h>
#include <hip/hip_bf16.h>

#define B_DIM 256
#define T_DIM 512
#define K_DIM 128

typedef float f32x4 __attribute__((ext_vector_type(4)));

// One block (256 threads = 4 waves) per batch row b; the block runs BOTH
// passes (U = unclamped, C = gold-clamped) as two interleaved chains --
// independent dependency chains fill each other's latency stalls, share the
// emission loads/exp, and share one barrier per step.
// Thread t: k = t>>1, h = t&1 (j-half). Thread holds E[j][k]=exp(trans[j][k])
// for j in [64h,64h+64) as 16 pinned f32x4.
// Per step (single barrier, per chain):
//   s_half = sum_{j half} q[j]*E[j][k]; r_half = sum_{j half} q[j]
//   s = s_half + shfl_xor(s_half,1);  R = r_half + shfl_xor(r_half,1)
//   q'[k] = s * exp(e_t[k]) / R ;  m += log R
// => q_t[k] = exp(alpha_t[k] - LSE(alpha_{t-1})): |log q| <= ~15, stable.
__global__ __attribute__((amdgpu_flat_work_group_size(256, 256)))
__attribute__((amdgpu_waves_per_eu(1, 2)))
void crf_pass_kernel(
    const float* __restrict__ tw,      // [B,T,K]
    const float* __restrict__ trans,   // [K,K]
    const int*   __restrict__ gold,    // [B,T]
    const int*   __restrict__ lengths, // [B]
    float*       __restrict__ wsv)     // [B] : logZ_U - logZ_C
{
    const int b = blockIdx.x;
    const int tid = threadIdx.x;
    const int k = tid >> 1;            // 0..127
    const int h = tid & 1;             // j-half
    const int j0 = h * 64;

    __shared__ __align__(16) float qU[2][K_DIM];
    __shared__ __align__(16) float qC[2][K_DIM];
    __shared__ float redU[4], redC[4];

    // ---- E fragment: 16 named f32x4, pinned into VGPRs ----
    f32x4 E0, E1, E2, E3, E4, E5, E6, E7, E8, E9, E10, E11, E12, E13, E14, E15;
#define LOADE(n) { \
        const float* tp = &trans[(j0 + 4*(n)) * K_DIM + k]; \
        E##n.x = __expf(tp[0 * K_DIM]); \
        E##n.y = __expf(tp[1 * K_DIM]); \
        E##n.z = __expf(tp[2 * K_DIM]); \
        E##n.w = __expf(tp[3 * K_DIM]); }
    LOADE(0); LOADE(1); LOADE(2); LOADE(3);
    LOADE(4); LOADE(5); LOADE(6); LOADE(7);
    LOADE(8); LOADE(9); LOADE(10); LOADE(11);
    LOADE(12); LOADE(13); LOADE(14); LOADE(15);
#undef LOADE
    asm volatile("" : "+v"(E0), "+v"(E1), "+v"(E2), "+v"(E3),
                      "+v"(E4), "+v"(E5), "+v"(E6), "+v"(E7),
                      "+v"(E8), "+v"(E9), "+v"(E10), "+v"(E11),
                      "+v"(E12), "+v"(E13), "+v"(E14), "+v"(E15));

    const int len = lengths[b];
    const float* twb = tw + (size_t)b * T_DIM * K_DIM;
    const int* gb = gold + b * T_DIM;

    float mU = 0.0f, mC = 0.0f;
    float lastU, lastC;
    {
        float e0 = twb[k];
        int g = gb[0];
        float u = __expf(e0);
        float c = (g < 0 || g == k) ? u : 0.0f;
        if (h == 0) { qU[0][k] = u; qC[0][k] = c; }
        lastU = u; lastC = c;
    }
    __syncthreads();

    // prefetch emissions (shared by both chains) + gold for steps 1..4
    float ec[4]; int gc[4];
#pragma unroll
    for (int i = 0; i < 4; ++i) {
        int t = 1 + i; if (t > T_DIM - 1) t = T_DIM - 1;
        ec[i] = twb[t * K_DIM + k];
        gc[i] = gb[t];
    }

    for (int t0 = 1; t0 < len; t0 += 4) {
        float en[4]; int gn[4];
#pragma unroll
        for (int i = 0; i < 4; ++i) {
            int t = t0 + 4 + i; if (t > T_DIM - 1) t = T_DIM - 1;
            en[i] = twb[t * K_DIM + k];
            gn[i] = gb[t];
        }

#pragma unroll
        for (int i = 0; i < 4; ++i) {
            const int t = t0 + i;
            if (t < len) {             // block-uniform
                const int cur = (t - 1) & 1, nxt = t & 1;
                const f32x4* au = (const f32x4*)&qU[cur][j0];
                const f32x4* ac = (const f32x4*)&qC[cur][j0];
                float x = __expf(ec[i]);       // shared by both chains
                f32x4 sU = {0.f,0.f,0.f,0.f}, rU = {0.f,0.f,0.f,0.f};
                f32x4 sC = {0.f,0.f,0.f,0.f}, rC = {0.f,0.f,0.f,0.f};
#define Q4(n) { f32x4 a = au[n], c = ac[n]; \
                sU = __builtin_elementwise_fma(a, E##n, sU); rU += a; \
                sC = __builtin_elementwise_fma(c, E##n, sC); rC += c; }
                Q4(0);  Q4(1);  Q4(2);  Q4(3);
                Q4(4);  Q4(5);  Q4(6);  Q4(7);
                Q4(8);  Q4(9);  Q4(10); Q4(11);
                Q4(12); Q4(13); Q4(14); Q4(15);
#undef Q4
                float su = (sU.x + sU.y) + (sU.z + sU.w);
                float ru = (rU.x + rU.y) + (rU.z + rU.w);
                float sc = (sC.x + sC.y) + (sC.z + sC.w);
                float rc = (rC.x + rC.y) + (rC.z + rC.w);
                su += __shfl_xor(su, 1); ru += __shfl_xor(ru, 1);
                sc += __shfl_xor(sc, 1); rc += __shfl_xor(rc, 1);
                float qu_ = su * x * __builtin_amdgcn_rcpf(ru);
                float qc_ = sc * x * __builtin_amdgcn_rcpf(rc);
                int g = gc[i];
                if (g >= 0 && g != k) qc_ = 0.0f;
                mU += __logf(ru);
                mC += __logf(rc);
                if (h == 0) { qU[nxt][k] = qu_; qC[nxt][k] = qc_; }
                lastU = qu_; lastC = qc_;
            }
            __syncthreads();           // one barrier serves both chains
        }
#pragma unroll
        for (int i = 0; i < 4; ++i) { ec[i] = en[i]; gc[i] = gn[i]; }
    }

    // ---- final: wsv[b] = (mU + log sum qU) - (mC + log sum qC) ----
    float vU = (h == 0) ? lastU : 0.0f;
    float vC = (h == 0) ? lastC : 0.0f;
#pragma unroll
    for (int off = 1; off < 64; off <<= 1) {
        vU += __shfl_xor(vU, off);
        vC += __shfl_xor(vC, off);
    }
    if ((tid & 63) == 0) { redU[tid >> 6] = vU; redC[tid >> 6] = vC; }
    __syncthreads();
    if (tid == 0) {
        float SU = (redU[0] + redU[1]) + (redU[2] + redU[3]);
        float SC = (redC[0] + redC[1]) + (redC[2] + redC[3]);
        wsv[b] = (mU + __logf(SU)) - (mC + __logf(SC));
    }
}

__global__ void crf_finalize(const float* __restrict__ wsv, float* __restrict__ out)
{
    const int tid = threadIdx.x;   // 256 threads, one per batch row
    float d = wsv[tid];
#pragma unroll
    for (int off = 32; off; off >>= 1) d += __shfl_xor(d, off);
    __shared__ float red[4];
    if ((tid & 63) == 0) red[tid >> 6] = d;
    __syncthreads();
    if (tid == 0) out[0] = (red[0] + red[1] + red[2] + red[3]) * (1.0f / (float)B_DIM);
}

extern "C" void kernel_launch(void* const* d_in, const int* in_sizes, int n_in,
                              void* d_out, int out_size, void* d_ws, size_t ws_size,
                              hipStream_t stream)
{
    const float* tw      = (const float*)d_in[0];
    const float* trans   = (const float*)d_in[1];
    const int*   gold    = (const int*)d_in[2];
    const int*   lengths = (const int*)d_in[3];
    float* wsv = (float*)d_ws;          // B floats (per-row logZ diff)
    float* out = (float*)d_out;

    crf_pass_kernel<<<B_DIM, 256, 0, stream>>>(tw, trans, gold, lengths, wsv);
    crf_finalize<<<1, B_DIM, 0, stream>>>(wsv, out);
}

// Round 7
// 355.922 us; speedup vs baseline: 1.0952x; 1.0952x over previous
//
#include <hip/hip_runtime.h>
#include <hip/hip_bf16.h>

#define B_DIM 256
#define T_DIM 512
#define K_DIM 128

typedef float f32x4 __attribute__((ext_vector_type(4)));
typedef short bf16x8 __attribute__((ext_vector_type(8)));
typedef unsigned int u32;

// manual RNE float->bf16 (no dependence on header helpers)
__device__ __forceinline__ u32 bfround(float f) {
    u32 u = __builtin_bit_cast(u32, f);
    return (u + 0x7fffu + ((u >> 16) & 1u)) >> 16;
}
__device__ __forceinline__ short f2bf(float f) { return (short)bfround(f); }

// One block = one wave (64 lanes) = one batch row; BOTH passes (U = row 0,
// C = row 1) ride in the same 16x16x32 bf16 MFMAs.
//   lane: c = lane&15 (col / A-row id), g4 = lane>>4 (k-octet group)
// Persistent in VGPRs: Bf[kt][m] = bf16 B-fragment of E[k][n]=exp(trans),
//   k = 32*kt + 8*g4 + i, n = 16*m + c   (32 frags = 128 VGPRs, pinned).
// Per step: q_{t-1} (f32, D-layout at lanes 0-15: qU/qC[m] for k=16m+c) is
// packed (U|C<<16 bf16) into 128-dword LDS, re-read in A-layout (v_perm
// selects U/C half by row parity), 32 MFMAs produce s = q*E for both rows,
// then emission multiply + gold clamp. Exact renorm every 4 steps.
// No barriers: single wave, LDS ops are in-order within a wave.
__global__ __attribute__((amdgpu_flat_work_group_size(64, 64)))
__attribute__((amdgpu_waves_per_eu(1, 1)))
void crf_pass_kernel(
    const float* __restrict__ tw,      // [B,T,K]
    const float* __restrict__ trans,   // [K,K]
    const int*   __restrict__ gold,    // [B,T]
    const int*   __restrict__ lengths, // [B]
    float*       __restrict__ wsv)     // [B] : logZ_U - logZ_C
{
    const int b = blockIdx.x;
    const int lane = threadIdx.x;      // 0..63
    const int c = lane & 15;
    const int g4 = lane >> 4;
    const u32 psel = (c & 1) ? 0x07060302u : 0x05040100u;  // v_perm: hi/lo half
    const f32x4 zero4 = {0.f, 0.f, 0.f, 0.f};

    __shared__ __align__(16) u32 qx[K_DIM];   // packed (bf16 U | bf16 C<<16)

    // ---- E as B-fragments (one-time) ----
    bf16x8 Bf[4][8];
#pragma unroll
    for (int kt = 0; kt < 4; ++kt)
#pragma unroll
        for (int m = 0; m < 8; ++m) {
            const float* ep = trans + (32 * kt + 8 * g4) * K_DIM + 16 * m + c;
            union { short s[8]; bf16x8 v; } bf_;
#pragma unroll
            for (int i = 0; i < 8; ++i) bf_.s[i] = f2bf(__expf(ep[i * K_DIM]));
            Bf[kt][m] = bf_.v;
        }
    // pin: prevent occupancy-driven sinking/remat of the 128-VGPR E block
    asm volatile("" : "+v"(Bf[0][0]), "+v"(Bf[0][1]), "+v"(Bf[0][2]), "+v"(Bf[0][3]),
                      "+v"(Bf[0][4]), "+v"(Bf[0][5]), "+v"(Bf[0][6]), "+v"(Bf[0][7]),
                      "+v"(Bf[1][0]), "+v"(Bf[1][1]), "+v"(Bf[1][2]), "+v"(Bf[1][3]),
                      "+v"(Bf[1][4]), "+v"(Bf[1][5]), "+v"(Bf[1][6]), "+v"(Bf[1][7]));
    asm volatile("" : "+v"(Bf[2][0]), "+v"(Bf[2][1]), "+v"(Bf[2][2]), "+v"(Bf[2][3]),
                      "+v"(Bf[2][4]), "+v"(Bf[2][5]), "+v"(Bf[2][6]), "+v"(Bf[2][7]),
                      "+v"(Bf[3][0]), "+v"(Bf[3][1]), "+v"(Bf[3][2]), "+v"(Bf[3][3]),
                      "+v"(Bf[3][4]), "+v"(Bf[3][5]), "+v"(Bf[3][6]), "+v"(Bf[3][7]));

    const int len = lengths[b];
    const float* twb = tw + (size_t)b * T_DIM * K_DIM;
    const int* gb = gold + b * T_DIM;

    float qU[8], qC[8], mU = 0.f, mC = 0.f;
    {
        int g = gb[0];
#pragma unroll
        for (int m = 0; m < 8; ++m) {
            float u = __expf(twb[16 * m + c]);
            qU[m] = u;
            qC[m] = (g < 0 || g == 16 * m + c) ? u : 0.f;
        }
    }

    // emission prefetch, 2 steps ahead (t=1, t=2 always in-bounds of [T])
    float eA[8], eB[8]; int gA, gB;
#pragma unroll
    for (int m = 0; m < 8; ++m) {
        eA[m] = twb[1 * K_DIM + 16 * m + c];
        eB[m] = twb[2 * K_DIM + 16 * m + c];
    }
    gA = gb[1]; gB = gb[2];

#define STEP(EBUF, GVAR, TT) { \
    const int tp_ = ((TT) + 2 > T_DIM - 1) ? (T_DIM - 1) : ((TT) + 2); \
    float tE_[8]; \
    _Pragma("unroll") \
    for (int m_ = 0; m_ < 8; ++m_) tE_[m_] = twb[tp_ * K_DIM + 16 * m_ + c]; \
    const int tG_ = gb[tp_]; \
    float x_[8]; \
    _Pragma("unroll") \
    for (int m_ = 0; m_ < 8; ++m_) x_[m_] = __expf(EBUF[m_]); \
    if (lane < 16) { \
        _Pragma("unroll") \
        for (int m_ = 0; m_ < 8; ++m_) { \
            u32 r_; \
            asm("v_cvt_pk_bf16_f32 %0, %1, %2" : "=v"(r_) : "v"(qU[m_]), "v"(qC[m_])); \
            qx[16 * m_ + c] = r_; \
        } \
    } \
    bf16x8 Af_[4]; \
    _Pragma("unroll") \
    for (int kt_ = 0; kt_ < 4; ++kt_) { \
        const uint4* qp_ = (const uint4*)(qx + 32 * kt_ + 8 * g4); \
        uint4 lo_ = qp_[0], hi_ = qp_[1]; \
        union { u32 w[4]; bf16x8 v; } af_; \
        af_.w[0] = __builtin_amdgcn_perm(lo_.y, lo_.x, psel); \
        af_.w[1] = __builtin_amdgcn_perm(lo_.w, lo_.z, psel); \
        af_.w[2] = __builtin_amdgcn_perm(hi_.y, hi_.x, psel); \
        af_.w[3] = __builtin_amdgcn_perm(hi_.w, hi_.z, psel); \
        Af_[kt_] = af_.v; \
    } \
    f32x4 D_[8]; \
    _Pragma("unroll") \
    for (int m_ = 0; m_ < 8; ++m_) \
        D_[m_] = __builtin_amdgcn_mfma_f32_16x16x32_bf16(Af_[0], Bf[0][m_], zero4, 0, 0, 0); \
    _Pragma("unroll") \
    for (int kt_ = 1; kt_ < 4; ++kt_) { \
        _Pragma("unroll") \
        for (int m_ = 0; m_ < 8; ++m_) \
            D_[m_] = __builtin_amdgcn_mfma_f32_16x16x32_bf16(Af_[kt_], Bf[kt_][m_], D_[m_], 0, 0, 0); \
    } \
    const int g_ = GVAR; \
    _Pragma("unroll") \
    for (int m_ = 0; m_ < 8; ++m_) { \
        qU[m_] = D_[m_].x * x_[m_]; \
        float qc_ = D_[m_].y * x_[m_]; \
        qC[m_] = (g_ < 0 || g_ == 16 * m_ + c) ? qc_ : 0.f; \
    } \
    if (((TT) & 3) == 0) { \
        float ru_ = ((qU[0]+qU[1])+(qU[2]+qU[3]))+((qU[4]+qU[5])+(qU[6]+qU[7])); \
        float rc_ = ((qC[0]+qC[1])+(qC[2]+qC[3]))+((qC[4]+qC[5])+(qC[6]+qC[7])); \
        _Pragma("unroll") \
        for (int o_ = 1; o_ <= 8; o_ <<= 1) { \
            ru_ += __shfl_xor(ru_, o_); rc_ += __shfl_xor(rc_, o_); \
        } \
        float iu_ = __builtin_amdgcn_rcpf(ru_); \
        float ic_ = __builtin_amdgcn_rcpf(rc_); \
        _Pragma("unroll") \
        for (int m_ = 0; m_ < 8; ++m_) { qU[m_] *= iu_; qC[m_] *= ic_; } \
        mU += __logf(ru_); mC += __logf(rc_); \
    } \
    _Pragma("unroll") \
    for (int m_ = 0; m_ < 8; ++m_) EBUF[m_] = tE_[m_]; \
    GVAR = tG_; \
}

    for (int t0 = 1; t0 < len; t0 += 2) {
        STEP(eA, gA, t0)
        if (t0 + 1 < len) STEP(eB, gB, t0 + 1)
    }
#undef STEP

    // logZ_U - logZ_C ; valid on lanes 0-15 (offsets <16 stay in-group)
    float su = ((qU[0]+qU[1])+(qU[2]+qU[3]))+((qU[4]+qU[5])+(qU[6]+qU[7]));
    float sc = ((qC[0]+qC[1])+(qC[2]+qC[3]))+((qC[4]+qC[5])+(qC[6]+qC[7]));
#pragma unroll
    for (int o = 1; o <= 8; o <<= 1) { su += __shfl_xor(su, o); sc += __shfl_xor(sc, o); }
    if (lane == 0) wsv[b] = (mU + __logf(su)) - (mC + __logf(sc));
}

__global__ void crf_finalize(const float* __restrict__ wsv, float* __restrict__ out)
{
    const int tid = threadIdx.x;   // 256 threads, one per batch row
    float d = wsv[tid];
#pragma unroll
    for (int off = 32; off; off >>= 1) d += __shfl_xor(d, off);
    __shared__ float red[4];
    if ((tid & 63) == 0) red[tid >> 6] = d;
    __syncthreads();
    if (tid == 0) out[0] = (red[0] + red[1] + red[2] + red[3]) * (1.0f / (float)B_DIM);
}

extern "C" void kernel_launch(void* const* d_in, const int* in_sizes, int n_in,
                              void* d_out, int out_size, void* d_ws, size_t ws_size,
                              hipStream_t stream)
{
    const float* tw      = (const float*)d_in[0];
    const float* trans   = (const float*)d_in[1];
    const int*   gold    = (const int*)d_in[2];
    const int*   lengths = (const int*)d_in[3];
    float* wsv = (float*)d_ws;          // B floats (per-row logZ diff)
    float* out = (float*)d_out;

    crf_pass_kernel<<<B_DIM, 64, 0, stream>>>(tw, trans, gold, lengths, wsv);
    crf_finalize<<<1, B_DIM, 0, stream>>>(wsv, out);
}

// Round 9
// 344.957 us; speedup vs baseline: 1.1300x; 1.0318x over previous
//
#include <hip/hip_runtime.h>
#include <hip/hip_bf16.h>

#define B_DIM 256
#define T_DIM 512
#define K_DIM 128

typedef float f32x4 __attribute__((ext_vector_type(4)));
typedef short bf16x8 __attribute__((ext_vector_type(8)));
typedef unsigned int u32;

// manual RNE float->bf16
__device__ __forceinline__ u32 bfround(float f) {
    u32 u = __builtin_bit_cast(u32, f);
    return (u + 0x7fffu + ((u >> 16) & 1u)) >> 16;
}
__device__ __forceinline__ short f2bf(float f) { return (short)bfround(f); }

// One block = one wave (64 lanes) = one batch row; BOTH passes (U = even MFMA
// rows, C = odd rows) ride in the same 16x16x32 bf16 MFMAs (round-7 verified
// body). This round: 4-deep SELF-REFILL emission pipeline -- each step
// consumes eb[i] (expf) then reloads eb[i] for t+4 in place. No rotation
// copies => no same-step vmcnt drain (round 7's ~1500 cyc/step stall);
// load-to-use distance = 4 steps >> HBM latency.
__global__ __attribute__((amdgpu_flat_work_group_size(64, 64)))
__attribute__((amdgpu_waves_per_eu(1, 1)))
void crf_pass_kernel(
    const float* __restrict__ tw,      // [B,T,K]
    const float* __restrict__ trans,   // [K,K]
    const int*   __restrict__ gold,    // [B,T]
    const int*   __restrict__ lengths, // [B]
    float*       __restrict__ wsv)     // [B] : logZ_U - logZ_C
{
    const int b = blockIdx.x;
    const int lane = threadIdx.x;      // 0..63
    const int c = lane & 15;
    const int g4 = lane >> 4;
    const u32 psel = (c & 1) ? 0x07060302u : 0x05040100u;  // v_perm: C/U half
    const f32x4 zero4 = {0.f, 0.f, 0.f, 0.f};

    __shared__ __align__(16) u32 qx[K_DIM];   // packed (bf16 U | bf16 C<<16)

    // ---- E as B-fragments (one-time) ----
    bf16x8 Bf[4][8];
#pragma unroll
    for (int kt = 0; kt < 4; ++kt)
#pragma unroll
        for (int m = 0; m < 8; ++m) {
            const float* ep = trans + (32 * kt + 8 * g4) * K_DIM + 16 * m + c;
            union { short s[8]; bf16x8 v; } bf_;
#pragma unroll
            for (int i = 0; i < 8; ++i) bf_.s[i] = f2bf(__expf(ep[i * K_DIM]));
            Bf[kt][m] = bf_.v;
        }
    asm volatile("" : "+v"(Bf[0][0]), "+v"(Bf[0][1]), "+v"(Bf[0][2]), "+v"(Bf[0][3]),
                      "+v"(Bf[0][4]), "+v"(Bf[0][5]), "+v"(Bf[0][6]), "+v"(Bf[0][7]),
                      "+v"(Bf[1][0]), "+v"(Bf[1][1]), "+v"(Bf[1][2]), "+v"(Bf[1][3]),
                      "+v"(Bf[1][4]), "+v"(Bf[1][5]), "+v"(Bf[1][6]), "+v"(Bf[1][7]));
    asm volatile("" : "+v"(Bf[2][0]), "+v"(Bf[2][1]), "+v"(Bf[2][2]), "+v"(Bf[2][3]),
                      "+v"(Bf[2][4]), "+v"(Bf[2][5]), "+v"(Bf[2][6]), "+v"(Bf[2][7]),
                      "+v"(Bf[3][0]), "+v"(Bf[3][1]), "+v"(Bf[3][2]), "+v"(Bf[3][3]),
                      "+v"(Bf[3][4]), "+v"(Bf[3][5]), "+v"(Bf[3][6]), "+v"(Bf[3][7]));

    const int len = lengths[b];
    const float* twb = tw + (size_t)b * T_DIM * K_DIM;
    const int* gb = gold + b * T_DIM;

    float qU[8], qC[8], mU = 0.f, mC = 0.f;
    {
        int g = gb[0];
#pragma unroll
        for (int m = 0; m < 8; ++m) {
            float u = __expf(twb[16 * m + c]);
            qU[m] = u;
            qC[m] = (g < 0 || g == 16 * m + c) ? u : 0.f;
        }
    }

    // ---- prime the 4-deep pipeline: eb[i] holds step 1+i ----
    float eb[4][8]; int gv[4];
#pragma unroll
    for (int i = 0; i < 4; ++i) {
        int t = 1 + i; if (t > T_DIM - 1) t = T_DIM - 1;
        const float* lp = twb + t * K_DIM + c;
#pragma unroll
        for (int m = 0; m < 8; ++m) eb[i][m] = lp[16 * m];
        gv[i] = gb[t];
    }

    for (int t0 = 1; t0 < len; t0 += 4) {
#pragma unroll
        for (int i = 0; i < 4; ++i) {
            const int t = t0 + i;
            if (t < len) {             // block-uniform
                // consume buffer i
                float x_[8];
#pragma unroll
                for (int m = 0; m < 8; ++m) x_[m] = __expf(eb[i][m]);
                const int g_ = gv[i];
                // self-refill buffer i for step t+4 (no copies, deep in flight)
                {
                    int tt = t + 4; if (tt > T_DIM - 1) tt = T_DIM - 1;
                    const float* lp = twb + tt * K_DIM + c;
#pragma unroll
                    for (int m = 0; m < 8; ++m) eb[i][m] = lp[16 * m];
                    gv[i] = gb[tt];
                }
                // q -> LDS (packed bf16 U|C), lanes 0-15 cover all 128 k
                if (lane < 16) {
#pragma unroll
                    for (int m = 0; m < 8; ++m) {
                        u32 r_;
                        asm("v_cvt_pk_bf16_f32 %0, %1, %2"
                            : "=v"(r_) : "v"(qU[m]), "v"(qC[m]));
                        qx[16 * m + c] = r_;
                    }
                }
                // A-fragments: row even = U, row odd = C (psel by row parity)
                bf16x8 Af[4];
#pragma unroll
                for (int kt = 0; kt < 4; ++kt) {
                    const uint4* qp = (const uint4*)(qx + 32 * kt + 8 * g4);
                    uint4 lo = qp[0], hi = qp[1];
                    union { u32 w[4]; bf16x8 v; } af;
                    af.w[0] = __builtin_amdgcn_perm(lo.y, lo.x, psel);
                    af.w[1] = __builtin_amdgcn_perm(lo.w, lo.z, psel);
                    af.w[2] = __builtin_amdgcn_perm(hi.y, hi.x, psel);
                    af.w[3] = __builtin_amdgcn_perm(hi.w, hi.z, psel);
                    Af[kt] = af.v;
                }
                // s = q * E for both chains (32 MFMAs)
                f32x4 D[8];
#pragma unroll
                for (int m = 0; m < 8; ++m)
                    D[m] = __builtin_amdgcn_mfma_f32_16x16x32_bf16(Af[0], Bf[0][m], zero4, 0, 0, 0);
#pragma unroll
                for (int kt = 1; kt < 4; ++kt)
#pragma unroll
                    for (int m = 0; m < 8; ++m)
                        D[m] = __builtin_amdgcn_mfma_f32_16x16x32_bf16(Af[kt], Bf[kt][m], D[m], 0, 0, 0);
                // emission multiply + gold clamp
#pragma unroll
                for (int m = 0; m < 8; ++m) {
                    qU[m] = D[m].x * x_[m];
                    float qc_ = D[m].y * x_[m];
                    qC[m] = (g_ < 0 || g_ == 16 * m + c) ? qc_ : 0.f;
                }
                // exact renorm every 4 steps (round-7 verified numerics)
                if ((t & 3) == 0) {
                    float ru = ((qU[0]+qU[1])+(qU[2]+qU[3]))+((qU[4]+qU[5])+(qU[6]+qU[7]));
                    float rc = ((qC[0]+qC[1])+(qC[2]+qC[3]))+((qC[4]+qC[5])+(qC[6]+qC[7]));
#pragma unroll
                    for (int o = 1; o <= 8; o <<= 1) {
                        ru += __shfl_xor(ru, o); rc += __shfl_xor(rc, o);
                    }
                    float iu = __builtin_amdgcn_rcpf(ru);
                    float ic = __builtin_amdgcn_rcpf(rc);
#pragma unroll
                    for (int m = 0; m < 8; ++m) { qU[m] *= iu; qC[m] *= ic; }
                    mU += __logf(ru); mC += __logf(rc);
                }
            }
        }
    }

    // logZ_U - logZ_C ; identical per 16-lane group (rows duplicated)
    float su = ((qU[0]+qU[1])+(qU[2]+qU[3]))+((qU[4]+qU[5])+(qU[6]+qU[7]));
    float sc = ((qC[0]+qC[1])+(qC[2]+qC[3]))+((qC[4]+qC[5])+(qC[6]+qC[7]));
#pragma unroll
    for (int o = 1; o <= 8; o <<= 1) { su += __shfl_xor(su, o); sc += __shfl_xor(sc, o); }
    if (lane == 0) wsv[b] = (mU + __logf(su)) - (mC + __logf(sc));
}

__global__ void crf_finalize(const float* __restrict__ wsv, float* __restrict__ out)
{
    const int tid = threadIdx.x;   // 256 threads, one per batch row
    float d = wsv[tid];
#pragma unroll
    for (int off = 32; off; off >>= 1) d += __shfl_xor(d, off);
    __shared__ float red[4];
    if ((tid & 63) == 0) red[tid >> 6] = d;
    __syncthreads();
    if (tid == 0) out[0] = (red[0] + red[1] + red[2] + red[3]) * (1.0f / (float)B_DIM);
}

extern "C" void kernel_launch(void* const* d_in, const int* in_sizes, int n_in,
                              void* d_out, int out_size, void* d_ws, size_t ws_size,
                              hipStream_t stream)
{
    const float* tw      = (const float*)d_in[0];
    const float* trans   = (const float*)d_in[1];
    const int*   gold    = (const int*)d_in[2];
    const int*   lengths = (const int*)d_in[3];
    float* wsv = (float*)d_ws;          // B floats (per-row logZ diff)
    float* out = (float*)d_out;

    crf_pass_kernel<<<B_DIM, 64, 0, stream>>>(tw, trans, gold, lengths, wsv);
    crf_finalize<<<1, B_DIM, 0, stream>>>(wsv, out);
}